// Round 1
// 122.600 us; speedup vs baseline: 1.0188x; 1.0188x over previous
//
#include <hip/hip_runtime.h>
#include <math.h>

#define V_SIZE 100000
#define E_DIM  128
#define B_SIZE 512
#define Q_LEN  32
#define D_LEN  256
#define K_NUM  21

// Kernel params (faithful to the reference's swapped sigma call):
// mus ascending: [-0.95, -0.85, ..., 0.85, 0.95, 1.0]
// sigmas descending: [0.1, 0.001 x 20]  -> k=0 broad (mu=-0.95), k>=1 sharp.
//
// Nearest-bin exactness: sharp sigma=1e-3 -> exp underflows to 0.0f once
// |mm-mu| > 0.01443; sharp mus are >=0.05 apart -> at most ONE sharp bin
// nonzero per mm. broad + nearest-sharp == all 21 bins, bit-exact.
//
// fp16-split matmul: a = hi + lo (both fp16). hi*hi + lo*hi + hi*lo drops only
// lo*lo (<=2^-22|a||b|) -> mm error ~1e-6, fp32-class (verified absmax 0).
//
// R5 structure (this round):
//  - single fused kernel: grid 512 blocks x 512 threads; waves 0-3 = pair 0,
//    waves 4-7 = pair 1. Both logits meet in LDS -> sigmoid in-block; the
//    knrm_final kernel + its graph node are gone.
//  - latency-first prologue: doc indices + chunk-0 doc rows are issued at
//    kernel entry, so query gather / doc-index gather / chunk-0 gather are
//    all in flight concurrently; chunk-0 fp16 conversion happens pre-barrier
//    (register-only). Removes ~2.5us of serially-exposed gather latency.
//  - barrier-free doc loop unchanged: wave owns 64 docs, B-fragments built in
//    registers straight from global, A staged once in LDS in fragment order.

typedef _Float16 half8_t  __attribute__((ext_vector_type(8)));
typedef float    float4_t __attribute__((ext_vector_type(4)));

__global__ __launch_bounds__(512, 4) void knrm_fused(
    const float* __restrict__ emb,
    const int* __restrict__ q1, const int* __restrict__ d1,
    const int* __restrict__ q2, const int* __restrict__ d2,
    const float* __restrict__ w1, const float* __restrict__ b1,
    const float* __restrict__ w2, const float* __restrict__ b2,
    const float* __restrict__ w3, const float* __restrict__ b3,
    float* __restrict__ out)
{
    const int b    = blockIdx.x;
    const int t    = threadIdx.x;            // 0..511
    const int tl   = t & 255;                // thread within pair-half
    const int pair = t >> 8;

    const int* __restrict__ qidx = pair ? q2 : q1;
    const int* __restrict__ didx = pair ? d2 : d1;

    __shared__ half8_t AfH[2][2][4][64];     // [pair][qt][s][lane] hi fragments
    __shared__ half8_t AfL[2][2][4][64];     // lo fragments
    __shared__ float rnq[2][Q_LEN];
    __shared__ float phis[2][Q_LEN][22];     // k = 0..20
    __shared__ float ko[2][K_NUM];
    __shared__ float logitL[2];

    const int lane = t & 63;
    const int w    = tl >> 6;                // wave within pair -> docs w*64..+63
    const int quad = lane >> 4;
    const int l15  = lane & 15;

    // ---- early index loads: query idx + all 4 doc-chunk indices in flight first
    const int qr = tl >> 3;                  // 0..31
    const int qc = tl & 7;                   // 16-float column block
    int qi = qidx[b * Q_LEN + qr];
    int dix[4];
    #pragma unroll
    for (int c = 0; c < 4; ++c) {
        int di = didx[b * D_LEN + w * 64 + c * 16 + l15];
        dix[c] = min(max(di, 0), V_SIZE - 1);
    }
    qi = min(max(qi, 0), V_SIZE - 1);

    // ---- query row load (in flight)
    const float4* src = (const float4*)(emb + (size_t)qi * E_DIM) + qc * 4;
    float4 v0 = src[0], v1 = src[1], v2 = src[2], v3 = src[3];

    // ---- chunk-0 doc rows: issue NOW, consumed after query processing
    const float4* dr0 = (const float4*)(emb + (size_t)dix[0] * E_DIM) + quad * 2;
    float4 cur[8];
    #pragma unroll
    for (int s = 0; s < 4; ++s) { cur[2*s] = dr0[s*8]; cur[2*s+1] = dr0[s*8+1]; }

    // ---- phis init (LDS only; overlaps outstanding loads)
    for (int i = tl; i < Q_LEN * 22; i += 256) ((float*)phis[pair])[i] = 0.f;

    // ---- query -> fp16 hi/lo fragments in LDS (+ rnq)
    {
        float fv[16] = {v0.x,v0.y,v0.z,v0.w, v1.x,v1.y,v1.z,v1.w,
                        v2.x,v2.y,v2.z,v2.w, v3.x,v3.y,v3.z,v3.w};
        float ss = 0.f;
        half8_t h0, h1, l0, l1;
        #pragma unroll
        for (int j = 0; j < 8; ++j) {
            ss = fmaf(fv[j], fv[j], ss);
            _Float16 h = (_Float16)fv[j];
            h0[j] = h; l0[j] = (_Float16)(fv[j] - (float)h);
        }
        #pragma unroll
        for (int j = 0; j < 8; ++j) {
            ss = fmaf(fv[8 + j], fv[8 + j], ss);
            _Float16 h = (_Float16)fv[8 + j];
            h1[j] = h; l1[j] = (_Float16)(fv[8 + j] - (float)h);
        }
        // fragment-order store: k-base qc*16 -> s = qc>>1, quad = (qc&1)*2 (+1)
        const int qt  = qr >> 4;
        const int lr  = qr & 15;
        const int s   = qc >> 1;
        const int qd0 = (qc & 1) * 2;
        AfH[pair][qt][s][qd0 * 16 + lr]       = h0;
        AfH[pair][qt][s][(qd0 + 1) * 16 + lr] = h1;
        AfL[pair][qt][s][qd0 * 16 + lr]       = l0;
        AfL[pair][qt][s][(qd0 + 1) * 16 + lr] = l1;
        ss += __shfl_xor(ss, 1, 8);
        ss += __shfl_xor(ss, 2, 8);
        ss += __shfl_xor(ss, 4, 8);
        if (qc == 0) rnq[pair][qr] = 1.0f / fmaxf(sqrtf(ss), 1e-8f);
    }

    half8_t bh[4], bl[4];
    float rnd;

    // convert helper: 8x float4 (k-slices s*32+quad*8) -> B frags + own-row norm
    auto convert = [&](const float4* v) {
        float ss = 0.f;
        #pragma unroll
        for (int s = 0; s < 4; ++s) {
            float f[8] = {v[2*s].x, v[2*s].y, v[2*s].z, v[2*s].w,
                          v[2*s+1].x, v[2*s+1].y, v[2*s+1].z, v[2*s+1].w};
            half8_t h, l;
            #pragma unroll
            for (int j = 0; j < 8; ++j) {
                ss = fmaf(f[j], f[j], ss);
                _Float16 hh = (_Float16)f[j];
                h[j] = hh; l[j] = (_Float16)(f[j] - (float)hh);
            }
            bh[s] = h; bl[s] = l;
        }
        ss += __shfl_xor(ss, 16);   // quad bit 0
        ss += __shfl_xor(ss, 32);   // quad bit 1
        rnd = 1.0f / fmaxf(sqrtf(ss), 1e-8f);
    };

    // chunk-0 conversion: register-only, no LDS dependency -> before barrier
    convert(cur);

    __syncthreads();

    float rnqv[8];
    #pragma unroll
    for (int i = 0; i < 8; ++i)
        rnqv[i] = rnq[pair][(i >> 2) * 16 + quad * 4 + (i & 3)];

    const float cc0 = -0.5f / (0.1f * 0.1f);
    const float ccs = -0.5f / (0.001f * 0.001f);
    float breg[8] = {0.f,0.f,0.f,0.f,0.f,0.f,0.f,0.f};

    // ---- barrier-free doc loop: 4 chunks of 16 docs
    #pragma unroll
    for (int c = 0; c < 4; ++c) {
        float4 nx[8];
        if (c < 3) {
            const float4* dr = (const float4*)(emb + (size_t)dix[c+1] * E_DIM) + quad * 2;
            #pragma unroll
            for (int s = 0; s < 4; ++s) { nx[2*s] = dr[s*8]; nx[2*s+1] = dr[s*8+1]; }
        }

        float4_t acc0 = {0.f,0.f,0.f,0.f}, acc1 = {0.f,0.f,0.f,0.f};
        #pragma unroll
        for (int s = 0; s < 4; ++s) {
            half8_t a0h = AfH[pair][0][s][lane], a0l = AfL[pair][0][s][lane];
            half8_t a1h = AfH[pair][1][s][lane], a1l = AfL[pair][1][s][lane];
            acc0 = __builtin_amdgcn_mfma_f32_16x16x32_f16(a0h, bh[s], acc0, 0, 0, 0);
            acc1 = __builtin_amdgcn_mfma_f32_16x16x32_f16(a1h, bh[s], acc1, 0, 0, 0);
            acc0 = __builtin_amdgcn_mfma_f32_16x16x32_f16(a0l, bh[s], acc0, 0, 0, 0);
            acc1 = __builtin_amdgcn_mfma_f32_16x16x32_f16(a1l, bh[s], acc1, 0, 0, 0);
            acc0 = __builtin_amdgcn_mfma_f32_16x16x32_f16(a0h, bl[s], acc0, 0, 0, 0);
            acc1 = __builtin_amdgcn_mfma_f32_16x16x32_f16(a1h, bl[s], acc1, 0, 0, 0);
        }

        // epilogue: mm -> broad reg-accum + nearest sharp bin atomic
        #pragma unroll
        for (int qt = 0; qt < 2; ++qt) {
            const float4_t acc = qt ? acc1 : acc0;
            #pragma unroll
            for (int r = 0; r < 4; ++r) {
                const float mm = acc[r] * rnqv[qt*4 + r] * rnd;
                const float x0 = mm + 0.95f;
                breg[qt*4 + r] += __expf(x0 * x0 * cc0);
                float g = rintf((mm + 0.85f) * 10.f);
                g = fminf(fmaxf(g, 0.f), 18.f);
                float mu = fmaf(g, 0.1f, -0.85f);
                int ks = (int)g + 1;
                if (mm > 0.975f) { mu = 1.0f; ks = 20; }
                const float xs = mm - mu;
                const float es = __expf(xs * xs * ccs);
                if (es > 0.f) atomicAdd(&phis[pair][qt*16 + quad*4 + r][ks], es);
            }
        }

        if (c < 3) convert(nx);   // next chunk's frags + rnd (after epilogue used rnd)
    }

    // ---- broad-bin: reduce across the 16 lanes sharing each q
    #pragma unroll
    for (int i = 0; i < 8; ++i) {
        float v = breg[i];
        v += __shfl_xor(v, 1, 16);
        v += __shfl_xor(v, 2, 16);
        v += __shfl_xor(v, 4, 16);
        v += __shfl_xor(v, 8, 16);
        if (l15 == 0) atomicAdd(&phis[pair][(i >> 2) * 16 + quad * 4 + (i & 3)][0], v);
    }
    __syncthreads();

    // ---- ko[k] = sum_q log1p(phis[q][k])
    for (int p = tl; p < K_NUM * Q_LEN; p += 256) {
        const int q = p & 31;
        const int k = p >> 5;
        float l = log1pf(phis[pair][q][k]);
        l += __shfl_xor(l, 1, 32);
        l += __shfl_xor(l, 2, 32);
        l += __shfl_xor(l, 4, 32);
        l += __shfl_xor(l, 8, 32);
        l += __shfl_xor(l, 16, 32);
        if (q == 0) ko[pair][k] = l;
    }
    __syncthreads();

    // ---- MLP 21 -> 10 -> 5 -> 1 (one leader thread per pair)
    if (tl == 0) {
        float x1v[10];
        #pragma unroll
        for (int i = 0; i < 10; ++i) {
            float s = b1[i];
            for (int k = 0; k < K_NUM; ++k) {
                float v = ko[pair][k] > 0.f ? ko[pair][k] : 0.f;
                s = fmaf(v, w1[k * 10 + i], s);
            }
            x1v[i] = s;
        }
        float x2v[5];
        #pragma unroll
        for (int i = 0; i < 5; ++i) {
            float s = b2[i];
            #pragma unroll
            for (int k = 0; k < 10; ++k) {
                float v = x1v[k] > 0.f ? x1v[k] : 0.f;
                s = fmaf(v, w2[k * 5 + i], s);
            }
            x2v[i] = s;
        }
        float s3 = b3[0];
        #pragma unroll
        for (int k = 0; k < 5; ++k) {
            float v = x2v[k] > 0.f ? x2v[k] : 0.f;
            s3 = fmaf(v, w3[k], s3);
        }
        logitL[pair] = s3;
    }
    __syncthreads();

    // ---- final: sigmoid(logit1 - logit2), in-block (knrm_final eliminated)
    if (t == 0) {
        const float dl = logitL[0] - logitL[1];
        out[b] = 1.0f / (1.0f + __expf(-dl));
    }
}

extern "C" void kernel_launch(void* const* d_in, const int* in_sizes, int n_in,
                              void* d_out, int out_size, void* d_ws, size_t ws_size,
                              hipStream_t stream)
{
    const float* emb = (const float*)d_in[0];
    const float* w1  = (const float*)d_in[1];
    const float* b1  = (const float*)d_in[2];
    const float* w2  = (const float*)d_in[3];
    const float* b2  = (const float*)d_in[4];
    const float* w3  = (const float*)d_in[5];
    const float* b3  = (const float*)d_in[6];
    const int*   q1  = (const int*)d_in[7];
    const int*   d1  = (const int*)d_in[8];
    const int*   q2  = (const int*)d_in[9];
    const int*   d2  = (const int*)d_in[10];

    float* out = (float*)d_out;              // [B_SIZE]
    (void)d_ws; (void)ws_size;

    knrm_fused<<<dim3(B_SIZE), 512, 0, stream>>>(emb, q1, d1, q2, d2,
                                                 w1, b1, w2, b2, w3, b3, out);
}